// Round 1
// 386.924 us; speedup vs baseline: 1.0400x; 1.0400x over previous
//
#include <hip/hip_runtime.h>
#include <cstdint>
#include <cstddef>

// Problem constants
#define Bb 8
#define Tt 2048
#define Cc 1024
#define Dd 1024
#define Mm (Bb*Tt)   // 16384 rows
#define CL 64        // wkv chunk length
#define NCH (Tt/CL)  // 32 chunks

// NOTES:
// - inputs/outputs fp32. Keep d_ws <= 160 MB unless ws_size says otherwise
//   (160 proven safe, 344 aborted) -> merged-GEMM path gated on ws_size>=204MB.
// - R4: wkv 3-pass parallel scan (318us -> ~40us total).
// - R5: XOR swizzle killed 4.19M LDS bank conflicts but GEMM unchanged ->
//   conflicts were hidden under exposed HBM latency (~2100 cyc/K-iter).
// - R6: LDS double-buffer + merged 3-proj GEMM dispatch. Landed 603 TF on
//   gemm3 (MfmaUtil 26%) = the m97-structure vmcnt(0)-drain ceiling.
// - R7: 256x256 tile, 512 thr (8 waves, per-wave 128x64), TRIPLE-buffered
//   LDS (96 KB), counted s_waitcnt vmcnt(4) + raw s_barrier (1 barrier per
//   K-tile, never drain to 0 in the loop), s_setprio around MFMA cluster,
//   bijective XCD block swizzle. Staging/read swizzle identical to R5/R6
//   (verified 0 bank conflicts, identical FP accumulation order).

typedef __bf16  bf16x8  __attribute__((ext_vector_type(8)));
typedef float   floatx4 __attribute__((ext_vector_type(4)));

__device__ __forceinline__ ushort f2bf(float f) {
    unsigned u = __float_as_uint(f);
    u = (u + 0x7FFF + ((u >> 16) & 1)) >> 16;   // RNE
    return (ushort)u;
}
__device__ __forceinline__ float bf2f(ushort u) {
    return __uint_as_float(((unsigned)u) << 16);
}

__device__ __forceinline__ void load_lds16(const void* g, void* l) {
    __builtin_amdgcn_global_load_lds((__attribute__((address_space(1))) void*)(g),
                                     (__attribute__((address_space(3))) void*)(l),
                                     16, 0, 0);
}

// ---------------- fused mix + time-shift: fp32 x -> bf16 xk,xv,xr ----------------
__global__ __launch_bounds__(256) void prep_mix3(
        const float* __restrict__ x,
        const float* __restrict__ mk, const float* __restrict__ mv,
        const float* __restrict__ mr,
        ushort* __restrict__ xk, ushort* __restrict__ xv, ushort* __restrict__ xr) {
    int i  = blockIdx.x * 256 + threadIdx.x;     // vec8 chunk id, Mm*Cc/8 total
    int cq = i & (Cc / 8 - 1);                   // 128 vec8 per row
    int m  = i >> 7;
    int t  = m & (Tt - 1);
    float xc[8], xp[8];
    *(float4*)&xc[0] = ((const float4*)x)[i * 2];
    *(float4*)&xc[4] = ((const float4*)x)[i * 2 + 1];
    if (t != 0) {
        *(float4*)&xp[0] = ((const float4*)x)[(i - Cc / 8) * 2];
        *(float4*)&xp[4] = ((const float4*)x)[(i - Cc / 8) * 2 + 1];
    } else {
#pragma unroll
        for (int j = 0; j < 8; j++) xp[j] = 0.f;
    }
    float wk[8], wv[8], wr[8];
    *(float4*)&wk[0] = ((const float4*)mk)[cq * 2];
    *(float4*)&wk[4] = ((const float4*)mk)[cq * 2 + 1];
    *(float4*)&wv[0] = ((const float4*)mv)[cq * 2];
    *(float4*)&wv[4] = ((const float4*)mv)[cq * 2 + 1];
    *(float4*)&wr[0] = ((const float4*)mr)[cq * 2];
    *(float4*)&wr[4] = ((const float4*)mr)[cq * 2 + 1];
    ushort ok[8], ov[8], orr[8];
#pragma unroll
    for (int j = 0; j < 8; j++) {
        float d = xc[j] - xp[j];
        ok[j]  = f2bf(xp[j] + d * wk[j]);
        ov[j]  = f2bf(xp[j] + d * wv[j]);
        orr[j] = f2bf(xp[j] + d * wr[j]);
    }
    ((ulonglong2*)xk)[i] = *(const ulonglong2*)ok;
    ((ulonglong2*)xv)[i] = *(const ulonglong2*)ov;
    ((ulonglong2*)xr)[i] = *(const ulonglong2*)orr;
}

// ---------------- fp32 -> bf16 for the 4 weight matrices ----------------
__global__ __launch_bounds__(256) void cvt_w(
        const float* __restrict__ wk, const float* __restrict__ wv,
        const float* __restrict__ wr, const float* __restrict__ wo,
        ushort* __restrict__ ok, ushort* __restrict__ ov,
        ushort* __restrict__ orr, ushort* __restrict__ oo) {
    int i = blockIdx.x * 256 + threadIdx.x;       // vec4 units, 4 * 2^18 total
    int sel = i >> 18;
    int j = i & ((1 << 18) - 1);
    const float* s = sel == 0 ? wk : sel == 1 ? wv : sel == 2 ? wr : wo;
    ushort* d      = sel == 0 ? ok : sel == 1 ? ov : sel == 2 ? orr : oo;
    float4 f = ((const float4*)s)[j];
    ushort4 o;
    o.x = f2bf(f.x); o.y = f2bf(f.y); o.z = f2bf(f.z); o.w = f2bf(f.w);
    ((ushort4*)d)[j] = o;
}

// ======== shared GEMM core: 256x256 tile, BK=32, triple-buffered LDS ========
// 512 threads = 8 waves (4 m-rows x 2 n-cols), per-wave output 128x64.
// LDS per buffer: A 256x32 (16 KB) + B 256x32 (16 KB) = 32 KB; 3 buffers = 96 KB.
// Element layout per buffer: A at [0,8192), B at [8192,16384).
// Staging: pre-swizzled global source (spart) + linear global_load_lds dest;
// read with (quad ^ swz) granule XOR -> conflict-free (R5-verified scheme).
// Pipeline: prefetch runs 2 K-tiles ahead; per-iteration wait is
// s_waitcnt vmcnt(4) lgkmcnt(0) (counted, 4 loads of tile T+1 stay in
// flight) + ONE raw s_barrier. vmcnt(0) only on the peeled final tile.
struct GemmCore256 {
    floatx4 acc[8][4];
    int quad, fr, wm, wn;

    __device__ __forceinline__ void compute(const __bf16* __restrict__ Ac,
                                            int goff) {
        const __bf16* Bc = Ac + 8192;
        bf16x8 af[8], bfr[4];
#pragma unroll
        for (int mi = 0; mi < 8; mi++)
            af[mi] = *(const bf16x8*)&Ac[(wm + mi * 16 + fr) * 32 + goff];
#pragma unroll
        for (int ni = 0; ni < 4; ni++)
            bfr[ni] = *(const bf16x8*)&Bc[(wn + ni * 16 + fr) * 32 + goff];
        __builtin_amdgcn_s_setprio(1);
#pragma unroll
        for (int mi = 0; mi < 8; mi++)
#pragma unroll
            for (int ni = 0; ni < 4; ni++)
                acc[mi][ni] = __builtin_amdgcn_mfma_f32_16x16x32_bf16(
                    af[mi], bfr[ni], acc[mi][ni], 0, 0, 0);
        __builtin_amdgcn_s_setprio(0);
    }

    __device__ __forceinline__ void run(
            const ushort* __restrict__ A, const ushort* __restrict__ Bw,
            long tm, long tn, int Kdim, __bf16* LDSb) {
        const int tid  = threadIdx.x;
        const int lane = tid & 63;
        quad = lane >> 4;
        fr   = lane & 15;
        const int wave = tid >> 6;
        wm   = (wave >> 1) * 0;      // placeholder (set below)
        // wave arrangement: 4 m-rows x 2 n-cols
        wm   = (wave >> 1) * 0;      // (avoid compiler warning path)
        wm   = (wave & ~1) ? 0 : 0;  // no-op
        wm   = (wave >> 1) * 32;     // overwritten next line (kept simple):
        wm   = ((wave >> 1)) * 32;
        // Final (real) mapping:
        wm   = (wave >> 1) * 32;     // NOTE: real mapping assigned just below
        {
            const int wave_m = wave >> 1;   // 0..3 -> rows wave_m*... no:
            (void)wave_m;
        }
        // 8 waves as 2 (m) x 4 (n): per-wave 128 rows x 64 cols
        wm = (wave >> 2) * 128;      // wave_m in {0,1}
        wn = (wave & 3) * 64;        // wave_n in {0..3}
        const int swz  = (fr >> 1) & 3;
        const int goff = (quad ^ swz) * 8;

        // staging addresses (identical scheme to R5/R6, 512-thread variant)
        const int srow  = tid >> 2;                          // 0..127
        const int spart = (tid & 3) ^ ((tid >> 3) & 3);      // XOR pre-swizzle
        const ushort* Ag0 = A + (tm + srow) * (long)Kdim + spart * 8;
        const ushort* Ag1 = Ag0 + 128 * (long)Kdim;
        const ushort* Bg0 = Bw + (tn + srow) * (long)Kdim + spart * 8;
        const ushort* Bg1 = Bg0 + 128 * (long)Kdim;
        const int wlds = wave * 512;                         // elem offset

        floatx4 zero = {0.f, 0.f, 0.f, 0.f};
#pragma unroll
        for (int a1 = 0; a1 < 8; a1++)
#pragma unroll
            for (int b1 = 0; b1 < 4; b1++) acc[a1][b1] = zero;

        const int NT = Kdim >> 5;    // K-tiles of 32

        // prologue: stage tiles 0 and 1
        {
            __bf16* b0 = LDSb;
            load_lds16(Ag0,      b0 + wlds);
            load_lds16(Ag1,      b0 + 4096  + wlds);
            load_lds16(Bg0,      b0 + 8192  + wlds);
            load_lds16(Bg1,      b0 + 12288 + wlds);
            __bf16* b1 = LDSb + 16384;
            load_lds16(Ag0 + 32, b1 + wlds);
            load_lds16(Ag1 + 32, b1 + 4096  + wlds);
            load_lds16(Bg0 + 32, b1 + 8192  + wlds);
            load_lds16(Bg1 + 32, b1 + 12288 + wlds);
        }

        int bcur = 0, bst = 2;
        for (int T = 0; T < NT - 1; ++T) {
            // tile T landed (its 4 loads drained); tile T+1's 4 stay in flight
            asm volatile("s_waitcnt vmcnt(4) lgkmcnt(0)" ::: "memory");
            __builtin_amdgcn_s_barrier();
            asm volatile("" ::: "memory");
            if (T < NT - 2) {            // stage tile T+2 into freed buffer
                const int kt = (T + 2) << 5;
                __bf16* nb = LDSb + bst * 16384;
                load_lds16(Ag0 + kt, nb + wlds);
                load_lds16(Ag1 + kt, nb + 4096  + wlds);
                load_lds16(Bg0 + kt, nb + 8192  + wlds);
                load_lds16(Bg1 + kt, nb + 12288 + wlds);
            }
            compute(LDSb + bcur * 16384, goff);
            if (++bcur == 3) bcur = 0;
            if (++bst == 3) bst = 0;
        }
        // peeled final tile: nothing left to prefetch -> full drain is free
        asm volatile("s_waitcnt vmcnt(0) lgkmcnt(0)" ::: "memory");
        __builtin_amdgcn_s_barrier();
        asm volatile("" ::: "memory");
        compute(LDSb + bcur * 16384, goff);
    }
};

// bijective XCD-aware block swizzle; requires nwg % 8 == 0 and gridDim.x == 64
__device__ __forceinline__ int xcd_swizzle(int nwg) {
    const int orig  = blockIdx.y * 64 + blockIdx.x;
    const int chunk = nwg >> 3;
    return (orig & 7) * chunk + (orig >> 3);
}

// ---------------- single GEMM (used for Wo, and serial fallback) ----------------
// MODE: 0 = fp32 out, 1 = bf16 out, 2 = bf16 out + sigmoid, 3 = fp16 out
template<int MODE>
__global__ __launch_bounds__(512, 2) void gemm_nt(
        const ushort* __restrict__ A, const ushort* __restrict__ Bw,
        void* __restrict__ Co, int Ndim, int Kdim) {
    __shared__ __attribute__((aligned(16))) __bf16 LDSb[3 * 16384];  // 96 KB
    const int swz = xcd_swizzle(gridDim.x * gridDim.y);
    const long tm = (long)(swz & 63) * 256;
    const long tn = (long)(swz >> 6) * 256;
    GemmCore256 g;
    g.run(A, Bw, tm, tn, Kdim, LDSb);
#pragma unroll
    for (int mi = 0; mi < 8; mi++)
#pragma unroll
        for (int ni = 0; ni < 4; ni++)
#pragma unroll
            for (int r = 0; r < 4; r++) {
                long grow = tm + g.wm + mi * 16 + g.quad * 4 + r;
                long gcol = tn + g.wn + ni * 16 + g.fr;
                float v = g.acc[mi][ni][r];
                if (MODE == 2) v = 1.f / (1.f + __expf(-v));
                if (MODE == 0)      ((float*)Co)[grow * Ndim + gcol] = v;
                else if (MODE == 3) ((_Float16*)Co)[grow * Ndim + gcol] = (_Float16)v;
                else                ((ushort*)Co)[grow * Ndim + gcol] = f2bf(v);
            }
}

// ---------------- merged 3-projection GEMM (needs ws >= 204 MB) ----------------
// grid (64, 12): after swizzle, yt = proj*4 + ntile. proj 0->kb(fp16),
// 1->vb(bf16), 2->sb(sigmoid bf16).
__global__ __launch_bounds__(512, 2) void gemm3_nt(
        const ushort* __restrict__ xk, const ushort* __restrict__ xv,
        const ushort* __restrict__ xr,
        const ushort* __restrict__ wk, const ushort* __restrict__ wv,
        const ushort* __restrict__ wr,
        _Float16* __restrict__ kb, ushort* __restrict__ vb,
        ushort* __restrict__ sb) {
    __shared__ __attribute__((aligned(16))) __bf16 LDSb[3 * 16384];  // 96 KB
    const int swz = xcd_swizzle(64 * 12);
    const int mt  = swz & 63;
    const int yt  = swz >> 6;
    const int proj = yt >> 2;
    const long tm = (long)mt * 256;
    const long tn = (long)(yt & 3) * 256;
    const ushort* A  = proj == 0 ? xk : proj == 1 ? xv : xr;
    const ushort* Bw = proj == 0 ? wk : proj == 1 ? wv : wr;
    GemmCore256 g;
    g.run(A, Bw, tm, tn, Cc, LDSb);
#pragma unroll
    for (int mi = 0; mi < 8; mi++)
#pragma unroll
        for (int ni = 0; ni < 4; ni++)
#pragma unroll
            for (int r = 0; r < 4; r++) {
                long grow = tm + g.wm + mi * 16 + g.quad * 4 + r;
                long gcol = tn + g.wn + ni * 16 + g.fr;
                long off = grow * Dd + gcol;
                float v = g.acc[mi][ni][r];
                if (proj == 0)      kb[off] = (_Float16)v;
                else if (proj == 1) vb[off] = f2bf(v);
                else                sb[off] = f2bf(1.f / (1.f + __expf(-v)));
            }
}

// ---------------- WKV: 3-pass chunked parallel scan ----------------
__global__ __launch_bounds__(256) void wkv_part(
        const _Float16* __restrict__ kb, const ushort* __restrict__ vb,
        const float* __restrict__ decay,
        float* __restrict__ pa, float* __restrict__ pb) {
    int gid = blockIdx.x * 256 + threadIdx.x;   // 0..B*NCH*D-1, d fastest
    int d = gid & (Dd - 1);
    int c = (gid >> 10) & (NCH - 1);
    int b = gid >> 15;
    float ew = __expf(-__expf(decay[d]));
    size_t base = ((size_t)b * Tt + (size_t)c * CL) * Dd + d;
    float a = 0.f, bs = 0.f;
    for (int i0 = 0; i0 < CL; i0 += 8) {
        float kr[8], vr[8];
#pragma unroll
        for (int j = 0; j < 8; j++) {
            size_t idx = base + (size_t)(i0 + j) * Dd;
            kr[j] = (float)kb[idx]; vr[j] = bf2f(vb[idx]);
        }
#pragma unroll
        for (int j = 0; j < 8; j++) {
            float ek = __expf(kr[j]);
            a  = ew * a  + ek * vr[j];
            bs = ew * bs + ek;
        }
    }
    int sidx = c * (Bb * Dd) + b * Dd + d;      // [c][b][d]
    pa[sidx] = a; pb[sidx] = bs;
}

__global__ __launch_bounds__(256) void wkv_prefix(
        const float* __restrict__ pa, const float* __restrict__ pb,
        const float* __restrict__ decay,
        float* __restrict__ sa, float* __restrict__ sb) {
    int gid = blockIdx.x * 256 + threadIdx.x;   // 0..B*D-1
    int d = gid & (Dd - 1);
    float ewL = __expf(-__expf(decay[d]) * (float)CL);  // ew^CL, direct
    float ca = 0.f, cb = 0.f;
#pragma unroll
    for (int c = 0; c < NCH; c++) {
        int idx = c * (Bb * Dd) + gid;
        sa[idx] = ca; sb[idx] = cb;
        ca = ewL * ca + pa[idx];
        cb = ewL * cb + pb[idx];
    }
}

__global__ __launch_bounds__(256) void wkv_chunk(
        const _Float16* __restrict__ kb, const ushort* __restrict__ vb,
        const ushort* __restrict__ sr,
        const float* __restrict__ decay, const float* __restrict__ tf,
        const float* __restrict__ sa, const float* __restrict__ sb,
        ushort* __restrict__ rw) {
    int gid = blockIdx.x * 256 + threadIdx.x;
    int d = gid & (Dd - 1);
    int c = (gid >> 10) & (NCH - 1);
    int b = gid >> 15;
    float ew = __expf(-__expf(decay[d]));
    float eu = __expf(tf[d]);
    int sidx = c * (Bb * Dd) + b * Dd + d;
    float a = sa[sidx], bs = sb[sidx];
    size_t base = ((size_t)b * Tt + (size_t)c * CL) * Dd + d;
    for (int i0 = 0; i0 < CL; i0 += 8) {
        float kr[8], vr[8], rr[8];
#pragma unroll
        for (int j = 0; j < 8; j++) {
            size_t idx = base + (size_t)(i0 + j) * Dd;
            kr[j] = (float)kb[idx]; vr[j] = bf2f(vb[idx]); rr[j] = bf2f(sr[idx]);
        }
#pragma unroll
        for (int j = 0; j < 8; j++) {
            float ek  = __expf(kr[j]);
            float ekv = ek * vr[j];
            float out = (eu * ekv + a) / (eu * ek + bs);
            a  = ew * a  + ekv;
            bs = ew * bs + ek;
            rw[base + (size_t)(i0 + j) * Dd] = f2bf(rr[j] * out);
        }
    }
}

extern "C" void kernel_launch(void* const* d_in, const int* in_sizes, int n_in,
                              void* d_out, int out_size, void* d_ws, size_t ws_size,
                              hipStream_t stream) {
    (void)in_sizes; (void)n_in; (void)out_size;
    const float* x  = (const float*)d_in[0];
    const float* td = (const float*)d_in[1];
    const float* tf = (const float*)d_in[2];
    const float* mk = (const float*)d_in[3];
    const float* mv = (const float*)d_in[4];
    const float* mr = (const float*)d_in[5];
    const float* Wk = (const float*)d_in[6];
    const float* Wv = (const float*)d_in[7];
    const float* Wr = (const float*)d_in[8];
    const float* Wo = (const float*)d_in[9];
    float* out = (float*)d_out;

    const size_t xsz = (size_t)Mm * Cc * 2;           // 32 MB
    const size_t wsz = (size_t)Dd * Cc * 2;           // 2 MB
    const size_t ssz = (size_t)Bb * NCH * Dd * 4;     // 1 MB
    const size_t need_merged = 6 * xsz + 4 * wsz + 4 * ssz;   // ~204 MB

    char* p = (char*)d_ws;
    auto take = [&](size_t n) { char* r = p; p += n; return r; };
    ushort*   xk = (ushort*)take(xsz);
    ushort*   xv = (ushort*)take(xsz);
    ushort*   xr = (ushort*)take(xsz);
    _Float16* kb = (_Float16*)take(xsz);
    const bool merged = ws_size >= need_merged;
    ushort *vb, *sb, *rw;
    if (merged) {
        vb = (ushort*)take(xsz);
        sb = (ushort*)take(xsz);
        rw = xk;                       // xk dead after gemm3
    } else {
        vb = xk;                       // serial aliasing (R5 layout)
        sb = xv;
        rw = xr;
    }
    ushort* wk = (ushort*)take(wsz);
    ushort* wv = (ushort*)take(wsz);
    ushort* wr = (ushort*)take(wsz);
    ushort* wo = (ushort*)take(wsz);
    float*  pa = (float*)take(ssz);
    float*  pb = (float*)take(ssz);
    float*  sa = (float*)take(ssz);
    float*  sbst = (float*)take(ssz);

    dim3 g1(Mm / 256, Dd / 256);          // (64, 4)
    dim3 g2(Mm / 256, Cc / 256);          // (64, 4)
    dim3 g3(Mm / 256, 3 * Dd / 256);      // (64, 12)
    const int wkv_grid = (Bb * NCH * Dd) / 256;   // 1024

    cvt_w<<<4096, 256, 0, stream>>>(Wk, Wv, Wr, Wo, wk, wv, wr, wo);
    prep_mix3<<<Mm * Cc / 8 / 256, 256, 0, stream>>>(x, mk, mv, mr, xk, xv, xr);

    if (merged) {
        gemm3_nt<<<g3, 512, 0, stream>>>(xk, xv, xr, wk, wv, wr, kb, vb, sb);
    } else {
        gemm_nt<3><<<g1, 512, 0, stream>>>(xk, wk, kb, Dd, Cc);
        gemm_nt<1><<<g1, 512, 0, stream>>>(xv, wv, vb, Dd, Cc);
        gemm_nt<2><<<g1, 512, 0, stream>>>(xr, wr, sb, Dd, Cc);
    }

    wkv_part  <<<wkv_grid, 256, 0, stream>>>(kb, vb, td, pa, pb);
    wkv_prefix<<<(Bb * Dd) / 256, 256, 0, stream>>>(pa, pb, td, sa, sbst);
    wkv_chunk <<<wkv_grid, 256, 0, stream>>>(kb, vb, sb, td, tf, sa, sbst, rw);

    gemm_nt<0><<<g2, 512, 0, stream>>>(rw, wo, out, Cc, Dd);
}

// Round 2
// 380.708 us; speedup vs baseline: 1.0569x; 1.0163x over previous
//
#include <hip/hip_runtime.h>
#include <cstdint>
#include <cstddef>

// Problem constants
#define Bb 8
#define Tt 2048
#define Cc 1024
#define Dd 1024
#define Mm (Bb*Tt)   // 16384 rows
#define CL 64        // wkv chunk length
#define NCH (Tt/CL)  // 32 chunks

// NOTES:
// - inputs/outputs fp32. Workspace layout gated on ws_size>=204MB (merged path).
// - R4: wkv 3-pass parallel scan (318us -> ~40us total).
// - R5: XOR swizzle -> 0 LDS bank conflicts (verified by PMC).
// - R6: 128-tile dbuf merged GEMM: 603 TF, MfmaUtil 26 (vmcnt(0)-drain ceiling).
// - R7: 256-tile, counted vmcnt, triple buffer: 720 TF, MfmaUtil 30, VALUBusy 22.
//   Coarse K-tile phases leave ds_read/MFMA serialized (m196's documented trap).
// - R8: full 8-phase port: BK=64, 2x64KB LDS dbuf, 4 phases/K-tile
//   {ds_read quadrant -> bar -> setprio 16xMFMA -> bar}, all 8 prefetch loads
//   issued at phase 1, awaited at phase 4 (3 phases ~1800cyc in flight, no
//   mid-loop drain pressure), granule swizzle g^(fr&7) for 128B-stride rows,
//   proj-major XCD chunking for A-panel L2 reuse.

typedef __bf16  bf16x8  __attribute__((ext_vector_type(8)));
typedef float   floatx4 __attribute__((ext_vector_type(4)));

#define MFMA16(a, b, c) __builtin_amdgcn_mfma_f32_16x16x32_bf16((a), (b), (c), 0, 0, 0)

__device__ __forceinline__ ushort f2bf(float f) {
    unsigned u = __float_as_uint(f);
    u = (u + 0x7FFF + ((u >> 16) & 1)) >> 16;   // RNE
    return (ushort)u;
}
__device__ __forceinline__ float bf2f(ushort u) {
    return __uint_as_float(((unsigned)u) << 16);
}

__device__ __forceinline__ void load_lds16(const void* g, void* l) {
    __builtin_amdgcn_global_load_lds((__attribute__((address_space(1))) void*)(g),
                                     (__attribute__((address_space(3))) void*)(l),
                                     16, 0, 0);
}

#define CFENCE asm volatile("" ::: "memory")
#define BARRIER do { CFENCE; __builtin_amdgcn_s_barrier(); CFENCE; } while (0)

// ---------------- fused mix + time-shift: fp32 x -> bf16 xk,xv,xr ----------------
__global__ __launch_bounds__(256) void prep_mix3(
        const float* __restrict__ x,
        const float* __restrict__ mk, const float* __restrict__ mv,
        const float* __restrict__ mr,
        ushort* __restrict__ xk, ushort* __restrict__ xv, ushort* __restrict__ xr) {
    int i  = blockIdx.x * 256 + threadIdx.x;     // vec8 chunk id, Mm*Cc/8 total
    int cq = i & (Cc / 8 - 1);                   // 128 vec8 per row
    int m  = i >> 7;
    int t  = m & (Tt - 1);
    float xc[8], xp[8];
    *(float4*)&xc[0] = ((const float4*)x)[i * 2];
    *(float4*)&xc[4] = ((const float4*)x)[i * 2 + 1];
    if (t != 0) {
        *(float4*)&xp[0] = ((const float4*)x)[(i - Cc / 8) * 2];
        *(float4*)&xp[4] = ((const float4*)x)[(i - Cc / 8) * 2 + 1];
    } else {
#pragma unroll
        for (int j = 0; j < 8; j++) xp[j] = 0.f;
    }
    float wk[8], wv[8], wr[8];
    *(float4*)&wk[0] = ((const float4*)mk)[cq * 2];
    *(float4*)&wk[4] = ((const float4*)mk)[cq * 2 + 1];
    *(float4*)&wv[0] = ((const float4*)mv)[cq * 2];
    *(float4*)&wv[4] = ((const float4*)mv)[cq * 2 + 1];
    *(float4*)&wr[0] = ((const float4*)mr)[cq * 2];
    *(float4*)&wr[4] = ((const float4*)mr)[cq * 2 + 1];
    ushort ok[8], ov[8], orr[8];
#pragma unroll
    for (int j = 0; j < 8; j++) {
        float d = xc[j] - xp[j];
        ok[j]  = f2bf(xp[j] + d * wk[j]);
        ov[j]  = f2bf(xp[j] + d * wv[j]);
        orr[j] = f2bf(xp[j] + d * wr[j]);
    }
    ((ulonglong2*)xk)[i] = *(const ulonglong2*)ok;
    ((ulonglong2*)xv)[i] = *(const ulonglong2*)ov;
    ((ulonglong2*)xr)[i] = *(const ulonglong2*)orr;
}

// ---------------- fp32 -> bf16 for the 4 weight matrices ----------------
__global__ __launch_bounds__(256) void cvt_w(
        const float* __restrict__ wk, const float* __restrict__ wv,
        const float* __restrict__ wr, const float* __restrict__ wo,
        ushort* __restrict__ ok, ushort* __restrict__ ov,
        ushort* __restrict__ orr, ushort* __restrict__ oo) {
    int i = blockIdx.x * 256 + threadIdx.x;       // vec4 units, 4 * 2^18 total
    int sel = i >> 18;
    int j = i & ((1 << 18) - 1);
    const float* s = sel == 0 ? wk : sel == 1 ? wv : sel == 2 ? wr : wo;
    ushort* d      = sel == 0 ? ok : sel == 1 ? ov : sel == 2 ? orr : oo;
    float4 f = ((const float4*)s)[j];
    ushort4 o;
    o.x = f2bf(f.x); o.y = f2bf(f.y); o.z = f2bf(f.z); o.w = f2bf(f.w);
    ((ushort4*)d)[j] = o;
}

// ======== 8-phase GEMM core: 256x256 tile, BK=64, 2x64KB LDS dbuf ========
// 512 threads = 8 waves (2 m-halves x 4 n-cols); per-wave output 128x64.
// LDS buffer layout (elems): A [256][64] at 0, B [256][64] at 16384.
// Row r granule g (16B) stored at column g; DATA pre-swizzled at the global
// source so LDS[r][g] = G[r][g ^ (r&7)]; fragment read uses g_eff = g^(fr&7)
// -> even spread over all 32 banks (conflict-free, verified scheme family).
// Per K-tile: 4 phases over wave-tile quadrants:
//   p1: read A0(8)+B0(4); issue all 8 prefetch loads (T+1); bar; 16 MFMA; bar
//   p2: read B1(4);                                         bar; 16 MFMA; bar
//   p3: read A1(8);                                         bar; 16 MFMA; bar
//   p4: read B0(4, reload);  s_waitcnt vmcnt(0) [loads ~1800cyc old];
//                                                           bar; 16 MFMA; bar
// Prefetch loads stay in flight across 6 barriers; no mid-phase drains.
struct Gemm8P {
    floatx4 acc[8][4];
    int quad, fr, wm, wn;

    __device__ __forceinline__ void run(
            const ushort* __restrict__ A, const ushort* __restrict__ Bw,
            long tm, long tn, int Kdim, __bf16* LDSb) {
        const int tid  = threadIdx.x;
        const int lane = tid & 63;
        quad = lane >> 4;
        fr   = lane & 15;
        const int wave = tid >> 6;
        wm = (wave >> 2) * 128;          // m-half: 0 or 128
        wn = (wave & 3) * 64;            // n-col:  0,64,128,192
        const int x7 = fr & 7;
        const int g0 = (quad ^ x7) * 8;          // ks=0 granule elem offset
        const int g1 = ((4 + quad) ^ x7) * 8;    // ks=1

        // staging: thread covers row (tid>>3) of each 64-row load group,
        // source granule pre-swizzled by (row & 7)
        const int srow = tid >> 3;               // 0..63
        const int scol = ((tid & 7) ^ (srow & 7)) * 8;
        const int wlds = wave * 512;             // wave-uniform LDS elem base

        const ushort* Ag[4]; const ushort* Bg[4];
#pragma unroll
        for (int j = 0; j < 4; j++) {
            Ag[j] = A  + (tm + j * 64 + srow) * (long)Kdim + scol;
            Bg[j] = Bw + (tn + j * 64 + srow) * (long)Kdim + scol;
        }

        auto stage = [&](__bf16* buf, long koff) {
#pragma unroll
            for (int j = 0; j < 4; j++) {
                load_lds16(Ag[j] + koff, buf + j * 4096 + wlds);
                load_lds16(Bg[j] + koff, buf + 16384 + j * 4096 + wlds);
            }
        };

        floatx4 zero = {0.f, 0.f, 0.f, 0.f};
#pragma unroll
        for (int ai = 0; ai < 8; ai++)
#pragma unroll
            for (int nj = 0; nj < 4; nj++) acc[ai][nj] = zero;

        const int NT = Kdim >> 6;        // K-tiles of 64

        // prologue: issue tiles 0 and 1, publish tile 0
        stage(LDSb, 0);
        if (NT > 1) {
            stage(LDSb + 32768, 64);
            asm volatile("s_waitcnt vmcnt(8)" ::: "memory");
        } else {
            asm volatile("s_waitcnt vmcnt(0)" ::: "memory");
        }
        BARRIER;

        bf16x8 a0[4][2], a1[4][2], b0[2][2], b1[2][2];

        for (int T = 0; T < NT; ++T) {
            const __bf16* Ab = LDSb + (T & 1) * 32768;
            const __bf16* Bbf = Ab + 16384;

            // ---------- phase 1: A0 x B0 -> acc[0..3][0..1] ----------
#pragma unroll
            for (int mi = 0; mi < 4; mi++) {
                const __bf16* p = &Ab[(wm + mi * 16 + fr) * 64];
                a0[mi][0] = *(const bf16x8*)(p + g0);
                a0[mi][1] = *(const bf16x8*)(p + g1);
            }
#pragma unroll
            for (int ni = 0; ni < 2; ni++) {
                const __bf16* p = &Bbf[(wn + ni * 16 + fr) * 64];
                b0[ni][0] = *(const bf16x8*)(p + g0);
                b0[ni][1] = *(const bf16x8*)(p + g1);
            }
            if (T >= 1 && T + 1 < NT)    // tile 1 already issued in prologue
                stage(LDSb + ((T + 1) & 1) * 32768, (long)(T + 1) * 64);
            BARRIER;
            __builtin_amdgcn_s_setprio(1);
#pragma unroll
            for (int mi = 0; mi < 4; mi++)
#pragma unroll
                for (int ni = 0; ni < 2; ni++) {
                    acc[mi][ni] = MFMA16(a0[mi][0], b0[ni][0], acc[mi][ni]);
                    acc[mi][ni] = MFMA16(a0[mi][1], b0[ni][1], acc[mi][ni]);
                }
            __builtin_amdgcn_s_setprio(0);
            BARRIER;

            // ---------- phase 2: A0 x B1 -> acc[0..3][2..3] ----------
#pragma unroll
            for (int ni = 0; ni < 2; ni++) {
                const __bf16* p = &Bbf[(wn + 32 + ni * 16 + fr) * 64];
                b1[ni][0] = *(const bf16x8*)(p + g0);
                b1[ni][1] = *(const bf16x8*)(p + g1);
            }
            BARRIER;
            __builtin_amdgcn_s_setprio(1);
#pragma unroll
            for (int mi = 0; mi < 4; mi++)
#pragma unroll
                for (int ni = 0; ni < 2; ni++) {
                    acc[mi][2 + ni] = MFMA16(a0[mi][0], b1[ni][0], acc[mi][2 + ni]);
                    acc[mi][2 + ni] = MFMA16(a0[mi][1], b1[ni][1], acc[mi][2 + ni]);
                }
            __builtin_amdgcn_s_setprio(0);
            BARRIER;

            // ---------- phase 3: A1 x B1 -> acc[4..7][2..3] ----------
#pragma unroll
            for (int mi = 0; mi < 4; mi++) {
                const __bf16* p = &Ab[(wm + 64 + mi * 16 + fr) * 64];
                a1[mi][0] = *(const bf16x8*)(p + g0);
                a1[mi][1] = *(const bf16x8*)(p + g1);
            }
            BARRIER;
            __builtin_amdgcn_s_setprio(1);
#pragma unroll
            for (int mi = 0; mi < 4; mi++)
#pragma unroll
                for (int ni = 0; ni < 2; ni++) {
                    acc[4 + mi][2 + ni] = MFMA16(a1[mi][0], b1[ni][0], acc[4 + mi][2 + ni]);
                    acc[4 + mi][2 + ni] = MFMA16(a1[mi][1], b1[ni][1], acc[4 + mi][2 + ni]);
                }
            __builtin_amdgcn_s_setprio(0);
            BARRIER;

            // ---------- phase 4: A1 x B0 -> acc[4..7][0..1] ----------
#pragma unroll
            for (int ni = 0; ni < 2; ni++) {      // reload B0 (caps VGPR)
                const __bf16* p = &Bbf[(wn + ni * 16 + fr) * 64];
                b0[ni][0] = *(const bf16x8*)(p + g0);
                b0[ni][1] = *(const bf16x8*)(p + g1);
            }
            if (T + 1 < NT)   // next tile's loads: issued 3 phases ago
                asm volatile("s_waitcnt vmcnt(0)" ::: "memory");
            BARRIER;
            __builtin_amdgcn_s_setprio(1);
#pragma unroll
            for (int mi = 0; mi < 4; mi++)
#pragma unroll
                for (int ni = 0; ni < 2; ni++) {
                    acc[4 + mi][ni] = MFMA16(a1[mi][0], b0[ni][0], acc[4 + mi][ni]);
                    acc[4 + mi][ni] = MFMA16(a1[mi][1], b0[ni][1], acc[4 + mi][ni]);
                }
            __builtin_amdgcn_s_setprio(0);
            BARRIER;
        }
    }
};

// ---------------- single GEMM (used for Wo, and serial fallback) ----------------
// MODE: 0 = fp32 out, 1 = bf16 out, 2 = bf16 out + sigmoid, 3 = fp16 out
// grid (64, 4): XCD-chunked swizzle, 4 n-tiles of an m-tile adjacent.
template<int MODE>
__global__ __launch_bounds__(512, 2) void gemm_nt(
        const ushort* __restrict__ A, const ushort* __restrict__ Bw,
        void* __restrict__ Co, int Ndim, int Kdim) {
    __shared__ __attribute__((aligned(16))) __bf16 LDSb[2 * 32768];  // 128 KB
    const int orig = blockIdx.y * 64 + blockIdx.x;        // 0..255
    const int L    = (orig & 7) * 32 + (orig >> 3);       // contiguous per XCD
    const long tm = (long)(L >> 2) * 256;
    const long tn = (long)(L & 3) * 256;
    Gemm8P g;
    g.run(A, Bw, tm, tn, Kdim, LDSb);
#pragma unroll
    for (int ai = 0; ai < 8; ai++)
#pragma unroll
        for (int nj = 0; nj < 4; nj++)
#pragma unroll
            for (int r = 0; r < 4; r++) {
                long grow = tm + g.wm + ai * 16 + g.quad * 4 + r;
                long gcol = tn + g.wn + nj * 16 + g.fr;
                float v = g.acc[ai][nj][r];
                if (MODE == 2) v = 1.f / (1.f + __expf(-v));
                if (MODE == 0)      ((float*)Co)[grow * Ndim + gcol] = v;
                else if (MODE == 3) ((_Float16*)Co)[grow * Ndim + gcol] = (_Float16)v;
                else                ((ushort*)Co)[grow * Ndim + gcol] = f2bf(v);
            }
}

// ---------------- merged 3-projection GEMM (needs ws >= 204 MB) ----------------
// grid (64, 12) = 768 blocks; proj-major logical order L = proj*256 + mt*4 + nt,
// chunked 96/XCD so same-A-panel blocks co-reside on one XCD's L2.
__global__ __launch_bounds__(512, 2) void gemm3_nt(
        const ushort* __restrict__ xk, const ushort* __restrict__ xv,
        const ushort* __restrict__ xr,
        const ushort* __restrict__ wk, const ushort* __restrict__ wv,
        const ushort* __restrict__ wr,
        _Float16* __restrict__ kb, ushort* __restrict__ vb,
        ushort* __restrict__ sb) {
    __shared__ __attribute__((aligned(16))) __bf16 LDSb[2 * 32768];  // 128 KB
    const int orig = blockIdx.y * 64 + blockIdx.x;        // 0..767
    const int L    = (orig & 7) * 96 + (orig >> 3);
    const int proj = L >> 8;
    const int rem  = L & 255;
    const long tm = (long)(rem >> 2) * 256;
    const long tn = (long)(rem & 3) * 256;
    const ushort* A  = proj == 0 ? xk : proj == 1 ? xv : xr;
    const ushort* Bw = proj == 0 ? wk : proj == 1 ? wv : wr;
    Gemm8P g;
    g.run(A, Bw, tm, tn, Cc, LDSb);
#pragma unroll
    for (int ai = 0; ai < 8; ai++)
#pragma unroll
        for (int nj = 0; nj < 4; nj++)
#pragma unroll
            for (int r = 0; r < 4; r++) {
                long grow = tm + g.wm + ai * 16 + g.quad * 4 + r;
                long gcol = tn + g.wn + nj * 16 + g.fr;
                long off = grow * Dd + gcol;
                float v = g.acc[ai][nj][r];
                if (proj == 0)      kb[off] = (_Float16)v;
                else if (proj == 1) vb[off] = f2bf(v);
                else                sb[off] = f2bf(1.f / (1.f + __expf(-v)));
            }
}

// ---------------- WKV: 3-pass chunked parallel scan ----------------
__global__ __launch_bounds__(256) void wkv_part(
        const _Float16* __restrict__ kb, const ushort* __restrict__ vb,
        const float* __restrict__ decay,
        float* __restrict__ pa, float* __restrict__ pb) {
    int gid = blockIdx.x * 256 + threadIdx.x;   // 0..B*NCH*D-1, d fastest
    int d = gid & (Dd - 1);
    int c = (gid >> 10) & (NCH - 1);
    int b = gid >> 15;
    float ew = __expf(-__expf(decay[d]));
    size_t base = ((size_t)b * Tt + (size_t)c * CL) * Dd + d;
    float a = 0.f, bs = 0.f;
    for (int i0 = 0; i0 < CL; i0 += 8) {
        float kr[8], vr[8];
#pragma unroll
        for (int j = 0; j < 8; j++) {
            size_t idx = base + (size_t)(i0 + j) * Dd;
            kr[j] = (float)kb[idx]; vr[j] = bf2f(vb[idx]);
        }
#pragma unroll
        for (int j = 0; j < 8; j++) {
            float ek = __expf(kr[j]);
            a  = ew * a  + ek * vr[j];
            bs = ew * bs + ek;
        }
    }
    int sidx = c * (Bb * Dd) + b * Dd + d;      // [c][b][d]
    pa[sidx] = a; pb[sidx] = bs;
}

__global__ __launch_bounds__(256) void wkv_prefix(
        const float* __restrict__ pa, const float* __restrict__ pb,
        const float* __restrict__ decay,
        float* __restrict__ sa, float* __restrict__ sb) {
    int gid = blockIdx.x * 256 + threadIdx.x;   // 0..B*D-1
    int d = gid & (Dd - 1);
    float ewL = __expf(-__expf(decay[d]) * (float)CL);  // ew^CL, direct
    float ca = 0.f, cb = 0.f;
#pragma unroll
    for (int c = 0; c < NCH; c++) {
        int idx = c * (Bb * Dd) + gid;
        sa[idx] = ca; sb[idx] = cb;
        ca = ewL * ca + pa[idx];
        cb = ewL * cb + pb[idx];
    }
}

__global__ __launch_bounds__(256) void wkv_chunk(
        const _Float16* __restrict__ kb, const ushort* __restrict__ vb,
        const ushort* __restrict__ sr,
        const float* __restrict__ decay, const float* __restrict__ tf,
        const float* __restrict__ sa, const float* __restrict__ sb,
        ushort* __restrict__ rw) {
    int gid = blockIdx.x * 256 + threadIdx.x;
    int d = gid & (Dd - 1);
    int c = (gid >> 10) & (NCH - 1);
    int b = gid >> 15;
    float ew = __expf(-__expf(decay[d]));
    float eu = __expf(tf[d]);
    int sidx = c * (Bb * Dd) + b * Dd + d;
    float a = sa[sidx], bs = sb[sidx];
    size_t base = ((size_t)b * Tt + (size_t)c * CL) * Dd + d;
    for (int i0 = 0; i0 < CL; i0 += 8) {
        float kr[8], vr[8], rr[8];
#pragma unroll
        for (int j = 0; j < 8; j++) {
            size_t idx = base + (size_t)(i0 + j) * Dd;
            kr[j] = (float)kb[idx]; vr[j] = bf2f(vb[idx]); rr[j] = bf2f(sr[idx]);
        }
#pragma unroll
        for (int j = 0; j < 8; j++) {
            float ek  = __expf(kr[j]);
            float ekv = ek * vr[j];
            float out = (eu * ekv + a) / (eu * ek + bs);
            a  = ew * a  + ekv;
            bs = ew * bs + ek;
            rw[base + (size_t)(i0 + j) * Dd] = f2bf(rr[j] * out);
        }
    }
}

extern "C" void kernel_launch(void* const* d_in, const int* in_sizes, int n_in,
                              void* d_out, int out_size, void* d_ws, size_t ws_size,
                              hipStream_t stream) {
    (void)in_sizes; (void)n_in; (void)out_size;
    const float* x  = (const float*)d_in[0];
    const float* td = (const float*)d_in[1];
    const float* tf = (const float*)d_in[2];
    const float* mk = (const float*)d_in[3];
    const float* mv = (const float*)d_in[4];
    const float* mr = (const float*)d_in[5];
    const float* Wk = (const float*)d_in[6];
    const float* Wv = (const float*)d_in[7];
    const float* Wr = (const float*)d_in[8];
    const float* Wo = (const float*)d_in[9];
    float* out = (float*)d_out;

    const size_t xsz = (size_t)Mm * Cc * 2;           // 32 MB
    const size_t wsz = (size_t)Dd * Cc * 2;           // 2 MB
    const size_t ssz = (size_t)Bb * NCH * Dd * 4;     // 1 MB
    const size_t need_merged = 6 * xsz + 4 * wsz + 4 * ssz;   // ~204 MB

    char* p = (char*)d_ws;
    auto take = [&](size_t n) { char* r = p; p += n; return r; };
    ushort*   xk = (ushort*)take(xsz);
    ushort*   xv = (ushort*)take(xsz);
    ushort*   xr = (ushort*)take(xsz);
    _Float16* kb = (_Float16*)take(xsz);
    const bool merged = ws_size >= need_merged;
    ushort *vb, *sb, *rw;
    if (merged) {
        vb = (ushort*)take(xsz);
        sb = (ushort*)take(xsz);
        rw = xk;                       // xk dead after gemm3
    } else {
        vb = xk;                       // serial aliasing (R5 layout)
        sb = xv;
        rw = xr;
    }
    ushort* wk = (ushort*)take(wsz);
    ushort* wv = (ushort*)take(wsz);
    ushort* wr = (ushort*)take(wsz);
    ushort* wo = (ushort*)take(wsz);
    float*  pa = (float*)take(ssz);
    float*  pb = (float*)take(ssz);
    float*  sa = (float*)take(ssz);
    float*  sbst = (float*)take(ssz);

    dim3 g1(Mm / 256, Dd / 256);          // (64, 4)
    dim3 g2(Mm / 256, Cc / 256);          // (64, 4)
    dim3 g3(Mm / 256, 3 * Dd / 256);      // (64, 12)
    const int wkv_grid = (Bb * NCH * Dd) / 256;   // 1024

    cvt_w<<<4096, 256, 0, stream>>>(Wk, Wv, Wr, Wo, wk, wv, wr, wo);
    prep_mix3<<<Mm * Cc / 8 / 256, 256, 0, stream>>>(x, mk, mv, mr, xk, xv, xr);

    if (merged) {
        gemm3_nt<<<g3, 512, 0, stream>>>(xk, xv, xr, wk, wv, wr, kb, vb, sb);
    } else {
        gemm_nt<3><<<g1, 512, 0, stream>>>(xk, wk, kb, Dd, Cc);
        gemm_nt<1><<<g1, 512, 0, stream>>>(xv, wv, vb, Dd, Cc);
        gemm_nt<2><<<g1, 512, 0, stream>>>(xr, wr, sb, Dd, Cc);
    }

    wkv_part  <<<wkv_grid, 256, 0, stream>>>(kb, vb, td, pa, pb);
    wkv_prefix<<<(Bb * Dd) / 256, 256, 0, stream>>>(pa, pb, td, sa, sbst);
    wkv_chunk <<<wkv_grid, 256, 0, stream>>>(kb, vb, sb, td, tf, sa, sbst, rw);

    gemm_nt<0><<<g2, 512, 0, stream>>>(rw, wo, out, Cc, Dd);
}